// Round 1
// baseline (881.209 us; speedup 1.0000x reference)
//
#include <hip/hip_runtime.h>

typedef unsigned short u16;
typedef __attribute__((ext_vector_type(8))) short short8;
typedef __attribute__((ext_vector_type(4))) float f32x4;

#define N_TOK 16384
#define DIN   1024
#define NE    16
#define DEMB  128
#define H1N   1024
#define H2N   512
#define DOUT  512
#define CAP   34816   // 32768 entries + 16*128 padding
#define MT    (CAP/128)

// ---- workspace layout (bytes) ----
#define OFF_P      0ul          // 1024*16*4 = 65536
#define OFF_C      65536ul      // 16*4 (pad 256)
#define OFF_CTRL   65792ul      // counts[16]@0, fill[16]@64, poff[17]@128 (pad 256)
#define OFF_E01    66048ul      // 16384*2*4 = 131072
#define OFF_G01    197120ul     // 131072
#define OFF_GTOK   328192ul     // CAP*4 = 139264
#define OFF_GGATE  467456ul     // 139264
#define OFF_W1T    606720ul     // 16*1024*1024*2 = 33554432
#define OFF_W2T    34161152ul   // 16*512*1024*2 = 16777216
#define OFF_W3T    50938368ul   // 16*512*512*2  = 8388608
#define OFF_XG     59326976ul   // CAP*1024*2 = 71303168
#define OFF_H1     130630144ul  // CAP*1024*2 = 71303168  (ends ~202 MB)
#define OFF_H2     OFF_XG       // h2 aliases xg (disjoint lifetimes)

__device__ __forceinline__ u16 f2bf(float f) {
  union { float f; unsigned u; } v; v.f = f;
  unsigned r = v.u + 0x7fff + ((v.u >> 16) & 1);   // RNE, finite inputs
  return (u16)(r >> 16);
}

__device__ __forceinline__ void async_copy16(const u16* g, u16* l) {
  __builtin_amdgcn_global_load_lds((const __attribute__((address_space(1))) unsigned*)g,
                                   (__attribute__((address_space(3))) unsigned*)l,
                                   16, 0, 0);
}

// ---- K0: P = 2*Wr@emb^T [1024][16], c_e = 2*br.emb_e - |emb_e|^2 ----
__global__ void router_prep(const float* __restrict__ Wr, const float* __restrict__ br,
                            const float* __restrict__ emb, float* __restrict__ P,
                            float* __restrict__ c) {
  int idx = blockIdx.x * 256 + threadIdx.x;   // 16384 = 1024 rows * 16 experts
  int row = idx >> 4, e = idx & 15;
  float s = 0.f;
  for (int j = 0; j < DEMB; ++j) s += Wr[row * DEMB + j] * emb[e * DEMB + j];
  P[row * NE + e] = 2.f * s;
  if (idx < NE) {
    float cc = 0.f, n2 = 0.f;
    for (int j = 0; j < DEMB; ++j) {
      float ev = emb[idx * DEMB + j];
      cc += br[j] * ev;
      n2 += ev * ev;
    }
    c[idx] = 2.f * cc - n2;
  }
}

// ---- K1: scores, top-2, gates; counts via atomics ----
__global__ void router_score(const float* __restrict__ x, const float* __restrict__ P,
                             const float* __restrict__ c, int* __restrict__ e01,
                             float* __restrict__ g01, int* __restrict__ counts) {
  int wave = threadIdx.x >> 6, lane = threadIdx.x & 63;
  int e = lane & 15, kg = lane >> 4;     // lane role: expert e, k-group kg
  int tbase = blockIdx.x * 16 + wave * 4;
  float ce = c[e];

  const float* x0 = x + (size_t)(tbase + 0) * DIN + kg * 256;
  const float* x1 = x + (size_t)(tbase + 1) * DIN + kg * 256;
  const float* x2 = x + (size_t)(tbase + 2) * DIN + kg * 256;
  const float* x3 = x + (size_t)(tbase + 3) * DIN + kg * 256;
  const float* Pp = P + (size_t)(kg * 256) * NE + e;

  float a0 = 0.f, a1 = 0.f, a2 = 0.f, a3 = 0.f;
  #pragma unroll 8
  for (int i = 0; i < 256; ++i) {
    float pv = Pp[(size_t)i * NE];
    a0 = fmaf(x0[i], pv, a0);
    a1 = fmaf(x1[i], pv, a1);
    a2 = fmaf(x2[i], pv, a2);
    a3 = fmaf(x3[i], pv, a3);
  }
  float as[4] = {a0, a1, a2, a3};
  for (int ti = 0; ti < 4; ++ti) {
    float acc = as[ti];
    acc += __shfl_xor(acc, 16);
    acc += __shfl_xor(acc, 32);        // all lanes: full score for expert e
    float s = acc + ce;

    float s1 = s; int i1 = e;          // argmax, lower index wins ties
    #pragma unroll
    for (int off = 1; off < 16; off <<= 1) {
      float so = __shfl_xor(s1, off);
      int io = __shfl_xor(i1, off);
      if (so > s1 || (so == s1 && io < i1)) { s1 = so; i1 = io; }
    }
    float sm = (e == i1) ? -3.4e38f : s;
    float s2 = sm; int i2 = e;
    #pragma unroll
    for (int off = 1; off < 16; off <<= 1) {
      float so = __shfl_xor(s2, off);
      int io = __shfl_xor(i2, off);
      if (so > s2 || (so == s2 && io < i2)) { s2 = so; i2 = io; }
    }
    if (lane == 0) {
      int t = tbase + ti;
      float e1v = expf(s2 - s1);
      float g0 = 1.f / (1.f + e1v);
      float g1 = e1v / (1.f + e1v);
      e01[t * 2 + 0] = i1; e01[t * 2 + 1] = i2;
      g01[t * 2 + 0] = g0; g01[t * 2 + 1] = g1;
      atomicAdd(&counts[i1], 1);
      atomicAdd(&counts[i2], 1);
    }
  }
}

// ---- K2: padded offsets ----
__global__ void build_offsets(const int* __restrict__ counts, int* __restrict__ poff) {
  if (threadIdx.x == 0) {
    int off = 0;
    for (int e = 0; e < NE; ++e) {
      poff[e] = off;
      off += (counts[e] + 127) & ~127;
    }
    poff[NE] = off;
  }
}

// ---- K3: CSR entry lists ----
__global__ void build_lists(const int* __restrict__ e01, const float* __restrict__ g01,
                            const int* __restrict__ poff, int* __restrict__ fill,
                            int* __restrict__ gtok, float* __restrict__ ggate) {
  int t = blockIdx.x * 256 + threadIdx.x;
  #pragma unroll
  for (int k = 0; k < 2; ++k) {
    int e = e01[t * 2 + k];
    int pos = atomicAdd(&fill[e], 1);
    int idx = poff[e] + pos;
    gtok[idx] = t;
    ggate[idx] = g01[t * 2 + k];
  }
}

// ---- K4: gather x rows -> bf16 (zeros in padding) ----
__global__ void gather_x(const float* __restrict__ x, const int* __restrict__ poff,
                         const int* __restrict__ counts, const int* __restrict__ gtok,
                         u16* __restrict__ xg) {
  int row = blockIdx.x * 4 + (threadIdx.x >> 6);
  int lane = threadIdx.x & 63;
  int total = poff[NE];
  bool valid = false; int t = 0;
  if (row < total) {
    int e = 0;
    while (row >= poff[e + 1]) ++e;
    if (row - poff[e] < counts[e]) { valid = true; t = gtok[row]; }
  }
  u16* dst = xg + (size_t)row * DIN + lane * 16;
  if (valid) {
    const float* src = x + (size_t)t * DIN + lane * 16;
    #pragma unroll
    for (int j = 0; j < 4; ++j) {
      float4 v = ((const float4*)src)[j];
      ushort4 o;
      o.x = f2bf(v.x); o.y = f2bf(v.y); o.z = f2bf(v.z); o.w = f2bf(v.w);
      ((ushort4*)dst)[j] = o;
    }
  } else {
    ushort4 z = {0, 0, 0, 0};
    #pragma unroll
    for (int j = 0; j < 4; ++j) ((ushort4*)dst)[j] = z;
  }
}

// ---- K5: weight convert+transpose: [E][K][N] f32 -> [E][N][K] bf16 ----
template<int K, int N>
__global__ void conv_w(const float* __restrict__ W, u16* __restrict__ WT) {
  __shared__ float tile[64][65];
  int e = blockIdx.z;
  int n0 = blockIdx.x * 64, k0 = blockIdx.y * 64;
  int tx = threadIdx.x & 63, ty = threadIdx.x >> 6;
  const float* Wb = W + (size_t)e * K * N;
  #pragma unroll
  for (int p = 0; p < 16; ++p) {
    int k = p * 4 + ty;
    tile[k][tx] = Wb[(size_t)(k0 + k) * N + n0 + tx];
  }
  __syncthreads();
  u16* WTb = WT + (size_t)e * N * K;
  #pragma unroll
  for (int p = 0; p < 16; ++p) {
    int n = p * 4 + ty;
    WTb[(size_t)(n0 + n) * K + k0 + tx] = f2bf(tile[tx][n]);
  }
}

// ---- GEMM: A[rows][K] bf16 x B_e[N][K] bf16 (K-contig both) ----
// MODE 0: Cb = bf16(relu(acc+bias)); MODE 1: atomicAdd(out[token], gate*(acc+bias))
template<int MODE>
__global__ void __launch_bounds__(256)
gemm_moe(const u16* __restrict__ A, const u16* __restrict__ Ball,
         const float* __restrict__ bias, u16* __restrict__ Cb, float* __restrict__ outF,
         const int* __restrict__ poff, const int* __restrict__ counts,
         const int* __restrict__ gtok, const float* __restrict__ ggate,
         int K, int N) {
  __shared__ u16 Asm[4096];
  __shared__ u16 Bsm[4096];
  int row_base = blockIdx.y * 128;
  if (row_base >= poff[NE]) return;
  int e = 0;
  while (row_base >= poff[e + 1]) ++e;

  int tid = threadIdx.x;
  int wave = tid >> 6, lane = tid & 63;
  int wm = wave >> 1, wn = wave & 1;
  int fr = lane & 15, kq = lane >> 4;
  int n_base = blockIdx.x * 128;

  const u16* Arow = A + (size_t)row_base * K;
  const u16* Brow = Ball + (size_t)e * N * K + (size_t)n_base * K;

  f32x4 acc[4][4];
  #pragma unroll
  for (int m = 0; m < 4; ++m)
    #pragma unroll
    for (int n = 0; n < 4; ++n)
      acc[m][n] = (f32x4){0.f, 0.f, 0.f, 0.f};

  for (int kt = 0; kt < K; kt += 32) {
    __syncthreads();
    #pragma unroll
    for (int j = 0; j < 2; ++j) {
      int lin = j * 256 + tid;
      int r = lin >> 2, q = lin & 3;
      async_copy16(Arow + (size_t)r * K + kt + q * 8, Asm + lin * 8);
      async_copy16(Brow + (size_t)r * K + kt + q * 8, Bsm + lin * 8);
    }
    __syncthreads();
    short8 av[4], bv[4];
    #pragma unroll
    for (int m = 0; m < 4; ++m)
      av[m] = *(const short8*)(Asm + ((wm * 64 + m * 16 + fr) * 32 + kq * 8));
    #pragma unroll
    for (int n = 0; n < 4; ++n)
      bv[n] = *(const short8*)(Bsm + ((wn * 64 + n * 16 + fr) * 32 + kq * 8));
    #pragma unroll
    for (int m = 0; m < 4; ++m)
      #pragma unroll
      for (int n = 0; n < 4; ++n)
        acc[m][n] = __builtin_amdgcn_mfma_f32_16x16x32_bf16(av[m], bv[n], acc[m][n], 0, 0, 0);
  }

  int crow = (lane >> 4) * 4;   // C/D: col=lane&15, row=(lane>>4)*4+reg
  int ccol = lane & 15;
  const float* be = bias + (size_t)e * N;
  if constexpr (MODE == 0) {
    #pragma unroll
    for (int m = 0; m < 4; ++m) {
      int gr0 = row_base + wm * 64 + m * 16 + crow;
      #pragma unroll
      for (int n = 0; n < 4; ++n) {
        int gc = n_base + wn * 64 + n * 16 + ccol;
        float bvs = be[gc];
        #pragma unroll
        for (int r = 0; r < 4; ++r) {
          float v = acc[m][n][r] + bvs;
          v = v > 0.f ? v : 0.f;
          Cb[(size_t)(gr0 + r) * N + gc] = f2bf(v);
        }
      }
    }
  } else {
    int poe = poff[e], ce = counts[e];
    #pragma unroll
    for (int m = 0; m < 4; ++m) {
      int gr0 = row_base + wm * 64 + m * 16 + crow;
      int tk[4]; float gt[4]; bool vl[4];
      #pragma unroll
      for (int r = 0; r < 4; ++r) {
        int gr = gr0 + r;
        vl[r] = (gr - poe) < ce;
        tk[r] = vl[r] ? gtok[gr] : 0;
        gt[r] = vl[r] ? ggate[gr] : 0.f;
      }
      #pragma unroll
      for (int n = 0; n < 4; ++n) {
        int gc = n_base + wn * 64 + n * 16 + ccol;
        float bvs = be[gc];
        #pragma unroll
        for (int r = 0; r < 4; ++r) {
          if (vl[r]) {
            float v = (acc[m][n][r] + bvs) * gt[r];
            atomicAdd(outF + (size_t)tk[r] * N + gc, v);
          }
        }
      }
    }
  }
}

extern "C" void kernel_launch(void* const* d_in, const int* in_sizes, int n_in,
                              void* d_out, int out_size, void* d_ws, size_t ws_size,
                              hipStream_t stream) {
  const float* x   = (const float*)d_in[0];
  const float* Wr  = (const float*)d_in[1];
  const float* br  = (const float*)d_in[2];
  const float* emb = (const float*)d_in[3];
  const float* W1  = (const float*)d_in[4];
  const float* b1  = (const float*)d_in[5];
  const float* W2  = (const float*)d_in[6];
  const float* b2  = (const float*)d_in[7];
  const float* W3  = (const float*)d_in[8];
  const float* b3  = (const float*)d_in[9];
  float* out = (float*)d_out;
  char* ws = (char*)d_ws;

  float* P      = (float*)(ws + OFF_P);
  float* c      = (float*)(ws + OFF_C);
  int*   counts = (int*)(ws + OFF_CTRL);
  int*   fill   = (int*)(ws + OFF_CTRL + 64);
  int*   poff   = (int*)(ws + OFF_CTRL + 128);
  int*   e01    = (int*)(ws + OFF_E01);
  float* g01    = (float*)(ws + OFF_G01);
  int*   gtok   = (int*)(ws + OFF_GTOK);
  float* ggate  = (float*)(ws + OFF_GGATE);
  u16*   W1T    = (u16*)(ws + OFF_W1T);
  u16*   W2T    = (u16*)(ws + OFF_W2T);
  u16*   W3T    = (u16*)(ws + OFF_W3T);
  u16*   xg     = (u16*)(ws + OFF_XG);
  u16*   h1     = (u16*)(ws + OFF_H1);
  u16*   h2     = (u16*)(ws + OFF_H2);

  hipMemsetAsync(d_out, 0, (size_t)N_TOK * DOUT * sizeof(float), stream);
  hipMemsetAsync(ws + OFF_CTRL, 0, 128, stream);

  conv_w<DIN, H1N><<<dim3(H1N / 64, DIN / 64, NE), 256, 0, stream>>>(W1, W1T);
  conv_w<H1N, H2N><<<dim3(H2N / 64, H1N / 64, NE), 256, 0, stream>>>(W2, W2T);
  conv_w<H2N, DOUT><<<dim3(DOUT / 64, H2N / 64, NE), 256, 0, stream>>>(W3, W3T);

  router_prep<<<64, 256, 0, stream>>>(Wr, br, emb, P, c);
  router_score<<<1024, 256, 0, stream>>>(x, P, c, e01, g01, counts);
  build_offsets<<<1, 64, 0, stream>>>(counts, poff);
  build_lists<<<64, 256, 0, stream>>>(e01, g01, poff, fill, gtok, ggate);
  gather_x<<<CAP / 4, 256, 0, stream>>>(x, poff, counts, gtok, xg);

  gemm_moe<0><<<dim3(H1N / 128, MT), 256, 0, stream>>>(xg, W1T, b1, h1, nullptr,
                                                       poff, counts, nullptr, nullptr, DIN, H1N);
  gemm_moe<0><<<dim3(H2N / 128, MT), 256, 0, stream>>>(h1, W2T, b2, h2, nullptr,
                                                       poff, counts, nullptr, nullptr, H1N, H2N);
  gemm_moe<1><<<dim3(DOUT / 128, MT), 256, 0, stream>>>(h2, W3T, b3, nullptr, out,
                                                        poff, counts, gtok, ggate, H2N, DOUT);
}

// Round 2
// 864.979 us; speedup vs baseline: 1.0188x; 1.0188x over previous
//
#include <hip/hip_runtime.h>

typedef unsigned short u16;
typedef __attribute__((ext_vector_type(8))) short short8;
typedef __attribute__((ext_vector_type(4))) float f32x4;

#define N_TOK 16384
#define DIN   1024
#define NE    16
#define DEMB  128
#define H1N   1024
#define H2N   512
#define DOUT  512
#define CAP   34816   // 32768 entries + 16*128 padding
#define MT    (CAP/128)

// ---- workspace layout (bytes) ----
#define OFF_P      0ul          // 1024*16*4 = 65536
#define OFF_C      65536ul      // 16*4 (pad 256)
#define OFF_CTRL   65792ul      // counts[16]@0, fill[16]@64, poff[17]@128 (pad 256)
#define OFF_E01    66048ul      // 16384*2*4 = 131072
#define OFF_G01    197120ul     // 131072
#define OFF_GTOK   328192ul     // CAP*4 = 139264
#define OFF_GGATE  467456ul     // 139264
#define OFF_W1T    606720ul     // 16*1024*1024*2 = 33554432
#define OFF_W2T    34161152ul   // 16*512*1024*2 = 16777216
#define OFF_W3T    50938368ul   // 16*512*512*2  = 8388608
#define OFF_XG     59326976ul   // CAP*1024*2 = 71303168
#define OFF_H1     130630144ul  // CAP*1024*2 = 71303168  (ends ~202 MB)
#define OFF_H2     OFF_XG       // h2 aliases xg (disjoint lifetimes)

__device__ __forceinline__ u16 f2bf(float f) {
  union { float f; unsigned u; } v; v.f = f;
  unsigned r = v.u + 0x7fff + ((v.u >> 16) & 1);   // RNE, finite inputs
  return (u16)(r >> 16);
}

__device__ __forceinline__ void async_copy16(const u16* g, u16* l) {
  __builtin_amdgcn_global_load_lds((const __attribute__((address_space(1))) unsigned*)g,
                                   (__attribute__((address_space(3))) unsigned*)l,
                                   16, 0, 0);
}

// ---- K0: P = 2*Wr@emb^T [1024][16], c_e = 2*br.emb_e - |emb_e|^2 ----
__global__ void router_prep(const float* __restrict__ Wr, const float* __restrict__ br,
                            const float* __restrict__ emb, float* __restrict__ P,
                            float* __restrict__ c) {
  int idx = blockIdx.x * 256 + threadIdx.x;   // 16384 = 1024 rows * 16 experts
  int row = idx >> 4, e = idx & 15;
  float s = 0.f;
  for (int j = 0; j < DEMB; ++j) s += Wr[row * DEMB + j] * emb[e * DEMB + j];
  P[row * NE + e] = 2.f * s;
  if (idx < NE) {
    float cc = 0.f, n2 = 0.f;
    for (int j = 0; j < DEMB; ++j) {
      float ev = emb[idx * DEMB + j];
      cc += br[j] * ev;
      n2 += ev * ev;
    }
    c[idx] = 2.f * cc - n2;
  }
}

// ---- K1: scores, top-2, gates; counts via atomics ----
// Block = 4 waves, each wave owns 4 tokens. x rows staged coalesced into LDS;
// compute lanes: e-pair = lane&7 (experts 2e,2e+1), K-chunk = lane>>3 (128 floats).
// LDS reads rotated per chunk so the 8 chunk addresses tile all bank groups.
__global__ void __launch_bounds__(256) router_score(
    const float* __restrict__ x, const float* __restrict__ P,
    const float* __restrict__ c, int* __restrict__ e01,
    float* __restrict__ g01, int* __restrict__ counts) {
  __shared__ float xs[16384];   // 4 waves * 4 tokens * 1024 floats = 64 KB
  int wave = threadIdx.x >> 6, lane = threadIdx.x & 63;
  int e2 = lane & 7, kgl = lane >> 3;
  int tbase = blockIdx.x * 16 + wave * 4;
  float* xw = xs + wave * 4096;

  // stage 4 token rows, coalesced (1KB per wave-instr)
  #pragma unroll
  for (int t = 0; t < 4; ++t) {
    const float* src = x + (size_t)(tbase + t) * DIN;
    #pragma unroll
    for (int q = 0; q < 4; ++q) {
      int g = q * 256 + lane * 4;
      *(float4*)(xw + t * 1024 + g) = *(const float4*)(src + g);
    }
  }
  __syncthreads();

  int te0 = 2 * e2, te1 = te0 + 1;
  float ce0 = c[te0], ce1 = c[te1];
  const float* Pb = P + te0;          // P is [1024][16]

  float acc0[4] = {0.f, 0.f, 0.f, 0.f};
  float acc1[4] = {0.f, 0.f, 0.f, 0.f};
  int cbase = kgl * 128;
  #pragma unroll 4
  for (int i = 0; i < 32; ++i) {
    int w = (kgl * 4 + i * 4) & 127;   // rotation: conflict-free banks
    int idx = cbase + w;
    float2 pv0 = *(const float2*)(Pb + (size_t)(idx + 0) * NE);
    float2 pv1 = *(const float2*)(Pb + (size_t)(idx + 1) * NE);
    float2 pv2 = *(const float2*)(Pb + (size_t)(idx + 2) * NE);
    float2 pv3 = *(const float2*)(Pb + (size_t)(idx + 3) * NE);
    #pragma unroll
    for (int t = 0; t < 4; ++t) {
      float4 xv = *(const float4*)(xw + t * 1024 + idx);
      acc0[t] = fmaf(xv.x, pv0.x, acc0[t]); acc1[t] = fmaf(xv.x, pv0.y, acc1[t]);
      acc0[t] = fmaf(xv.y, pv1.x, acc0[t]); acc1[t] = fmaf(xv.y, pv1.y, acc1[t]);
      acc0[t] = fmaf(xv.z, pv2.x, acc0[t]); acc1[t] = fmaf(xv.z, pv2.y, acc1[t]);
      acc0[t] = fmaf(xv.w, pv3.x, acc0[t]); acc1[t] = fmaf(xv.w, pv3.y, acc1[t]);
    }
  }

  for (int t = 0; t < 4; ++t) {
    float s0 = acc0[t], s1 = acc1[t];
    // reduce over 8 K-chunks (lane bits 3..5)
    #pragma unroll
    for (int off = 8; off <= 32; off <<= 1) {
      s0 += __shfl_xor(s0, off);
      s1 += __shfl_xor(s1, off);
    }
    s0 += ce0; s1 += ce1;
    float hi; int hidx;
    if (s0 >= s1) { hi = s0; hidx = te0; } else { hi = s1; hidx = te1; }
    float m1 = hi; int i1 = hidx;
    #pragma unroll
    for (int off = 1; off < 8; off <<= 1) {
      float so = __shfl_xor(m1, off); int io = __shfl_xor(i1, off);
      if (so > m1 || (so == m1 && io < i1)) { m1 = so; i1 = io; }
    }
    float c2; int c2i;
    if (i1 == te0)      { c2 = s1; c2i = te1; }
    else if (i1 == te1) { c2 = s0; c2i = te0; }
    else                { c2 = hi; c2i = hidx; }
    float m2 = c2; int i2 = c2i;
    #pragma unroll
    for (int off = 1; off < 8; off <<= 1) {
      float so = __shfl_xor(m2, off); int io = __shfl_xor(i2, off);
      if (so > m2 || (so == m2 && io < i2)) { m2 = so; i2 = io; }
    }
    if (lane == 0) {
      int tok = tbase + t;
      float ev = expf(m2 - m1);
      float inv = 1.f / (1.f + ev);
      e01[tok * 2 + 0] = i1; e01[tok * 2 + 1] = i2;
      g01[tok * 2 + 0] = inv; g01[tok * 2 + 1] = ev * inv;
      atomicAdd(&counts[i1], 1);
      atomicAdd(&counts[i2], 1);
    }
  }
}

// ---- K2: padded offsets ----
__global__ void build_offsets(const int* __restrict__ counts, int* __restrict__ poff) {
  if (threadIdx.x == 0) {
    int off = 0;
    for (int e = 0; e < NE; ++e) {
      poff[e] = off;
      off += (counts[e] + 127) & ~127;
    }
    poff[NE] = off;
  }
}

// ---- K3: CSR entry lists ----
__global__ void build_lists(const int* __restrict__ e01, const float* __restrict__ g01,
                            const int* __restrict__ poff, int* __restrict__ fill,
                            int* __restrict__ gtok, float* __restrict__ ggate) {
  int t = blockIdx.x * 256 + threadIdx.x;
  #pragma unroll
  for (int k = 0; k < 2; ++k) {
    int e = e01[t * 2 + k];
    int pos = atomicAdd(&fill[e], 1);
    int idx = poff[e] + pos;
    gtok[idx] = t;
    ggate[idx] = g01[t * 2 + k];
  }
}

// ---- K4: gather x rows -> bf16 (zeros in padding) ----
__global__ void gather_x(const float* __restrict__ x, const int* __restrict__ poff,
                         const int* __restrict__ counts, const int* __restrict__ gtok,
                         u16* __restrict__ xg) {
  int row = blockIdx.x * 4 + (threadIdx.x >> 6);
  int lane = threadIdx.x & 63;
  int total = poff[NE];
  bool valid = false; int t = 0;
  if (row < total) {
    int e = 0;
    while (row >= poff[e + 1]) ++e;
    if (row - poff[e] < counts[e]) { valid = true; t = gtok[row]; }
  }
  u16* dst = xg + (size_t)row * DIN + lane * 16;
  if (valid) {
    const float* src = x + (size_t)t * DIN + lane * 16;
    #pragma unroll
    for (int j = 0; j < 4; ++j) {
      float4 v = ((const float4*)src)[j];
      ushort4 o;
      o.x = f2bf(v.x); o.y = f2bf(v.y); o.z = f2bf(v.z); o.w = f2bf(v.w);
      ((ushort4*)dst)[j] = o;
    }
  } else {
    ushort4 z = {0, 0, 0, 0};
    #pragma unroll
    for (int j = 0; j < 4; ++j) ((ushort4*)dst)[j] = z;
  }
}

// ---- K5: weight convert+transpose: [E][K][N] f32 -> [E][N][K] bf16 ----
template<int K, int N>
__global__ void conv_w(const float* __restrict__ W, u16* __restrict__ WT) {
  __shared__ float tile[64][65];
  int e = blockIdx.z;
  int n0 = blockIdx.x * 64, k0 = blockIdx.y * 64;
  int tx = threadIdx.x & 63, ty = threadIdx.x >> 6;
  const float* Wb = W + (size_t)e * K * N;
  #pragma unroll
  for (int p = 0; p < 16; ++p) {
    int k = p * 4 + ty;
    tile[k][tx] = Wb[(size_t)(k0 + k) * N + n0 + tx];
  }
  __syncthreads();
  u16* WTb = WT + (size_t)e * N * K;
  #pragma unroll
  for (int p = 0; p < 16; ++p) {
    int n = p * 4 + ty;
    WTb[(size_t)(n0 + n) * K + k0 + tx] = f2bf(tile[tx][n]);
  }
}

// ---- GEMM: A[rows][K] bf16 x B_e[N][K] bf16 (K-contig both) ----
// MODE 0: Cb = bf16(relu(acc+bias)); MODE 1: atomicAdd(out[token], gate*(acc+bias))
template<int MODE>
__global__ void __launch_bounds__(256)
gemm_moe(const u16* __restrict__ A, const u16* __restrict__ Ball,
         const float* __restrict__ bias, u16* __restrict__ Cb, float* __restrict__ outF,
         const int* __restrict__ poff, const int* __restrict__ counts,
         const int* __restrict__ gtok, const float* __restrict__ ggate,
         int K, int N) {
  __shared__ u16 Asm[4096];
  __shared__ u16 Bsm[4096];
  int row_base = blockIdx.y * 128;
  if (row_base >= poff[NE]) return;
  int e = 0;
  while (row_base >= poff[e + 1]) ++e;

  int tid = threadIdx.x;
  int wave = tid >> 6, lane = tid & 63;
  int wm = wave >> 1, wn = wave & 1;
  int fr = lane & 15, kq = lane >> 4;
  int n_base = blockIdx.x * 128;

  const u16* Arow = A + (size_t)row_base * K;
  const u16* Brow = Ball + (size_t)e * N * K + (size_t)n_base * K;

  f32x4 acc[4][4];
  #pragma unroll
  for (int m = 0; m < 4; ++m)
    #pragma unroll
    for (int n = 0; n < 4; ++n)
      acc[m][n] = (f32x4){0.f, 0.f, 0.f, 0.f};

  for (int kt = 0; kt < K; kt += 32) {
    __syncthreads();
    #pragma unroll
    for (int j = 0; j < 2; ++j) {
      int lin = j * 256 + tid;
      int r = lin >> 2, q = lin & 3;
      async_copy16(Arow + (size_t)r * K + kt + q * 8, Asm + lin * 8);
      async_copy16(Brow + (size_t)r * K + kt + q * 8, Bsm + lin * 8);
    }
    __syncthreads();
    short8 av[4], bv[4];
    #pragma unroll
    for (int m = 0; m < 4; ++m)
      av[m] = *(const short8*)(Asm + ((wm * 64 + m * 16 + fr) * 32 + kq * 8));
    #pragma unroll
    for (int n = 0; n < 4; ++n)
      bv[n] = *(const short8*)(Bsm + ((wn * 64 + n * 16 + fr) * 32 + kq * 8));
    #pragma unroll
    for (int m = 0; m < 4; ++m)
      #pragma unroll
      for (int n = 0; n < 4; ++n)
        acc[m][n] = __builtin_amdgcn_mfma_f32_16x16x32_bf16(av[m], bv[n], acc[m][n], 0, 0, 0);
  }

  int crow = (lane >> 4) * 4;   // C/D: col=lane&15, row=(lane>>4)*4+reg
  int ccol = lane & 15;
  const float* be = bias + (size_t)e * N;
  if constexpr (MODE == 0) {
    #pragma unroll
    for (int m = 0; m < 4; ++m) {
      int gr0 = row_base + wm * 64 + m * 16 + crow;
      #pragma unroll
      for (int n = 0; n < 4; ++n) {
        int gc = n_base + wn * 64 + n * 16 + ccol;
        float bvs = be[gc];
        #pragma unroll
        for (int r = 0; r < 4; ++r) {
          float v = acc[m][n][r] + bvs;
          v = v > 0.f ? v : 0.f;
          Cb[(size_t)(gr0 + r) * N + gc] = f2bf(v);
        }
      }
    }
  } else {
    int poe = poff[e], ce = counts[e];
    #pragma unroll
    for (int m = 0; m < 4; ++m) {
      int gr0 = row_base + wm * 64 + m * 16 + crow;
      int tk[4]; float gt[4]; bool vl[4];
      #pragma unroll
      for (int r = 0; r < 4; ++r) {
        int gr = gr0 + r;
        vl[r] = (gr - poe) < ce;
        tk[r] = vl[r] ? gtok[gr] : 0;
        gt[r] = vl[r] ? ggate[gr] : 0.f;
      }
      #pragma unroll
      for (int n = 0; n < 4; ++n) {
        int gc = n_base + wn * 64 + n * 16 + ccol;
        float bvs = be[gc];
        #pragma unroll
        for (int r = 0; r < 4; ++r) {
          if (vl[r]) {
            float v = (acc[m][n][r] + bvs) * gt[r];
            atomicAdd(outF + (size_t)tk[r] * N + gc, v);
          }
        }
      }
    }
  }
}

extern "C" void kernel_launch(void* const* d_in, const int* in_sizes, int n_in,
                              void* d_out, int out_size, void* d_ws, size_t ws_size,
                              hipStream_t stream) {
  const float* x   = (const float*)d_in[0];
  const float* Wr  = (const float*)d_in[1];
  const float* br  = (const float*)d_in[2];
  const float* emb = (const float*)d_in[3];
  const float* W1  = (const float*)d_in[4];
  const float* b1  = (const float*)d_in[5];
  const float* W2  = (const float*)d_in[6];
  const float* b2  = (const float*)d_in[7];
  const float* W3  = (const float*)d_in[8];
  const float* b3  = (const float*)d_in[9];
  float* out = (float*)d_out;
  char* ws = (char*)d_ws;

  float* P      = (float*)(ws + OFF_P);
  float* c      = (float*)(ws + OFF_C);
  int*   counts = (int*)(ws + OFF_CTRL);
  int*   fill   = (int*)(ws + OFF_CTRL + 64);
  int*   poff   = (int*)(ws + OFF_CTRL + 128);
  int*   e01    = (int*)(ws + OFF_E01);
  float* g01    = (float*)(ws + OFF_G01);
  int*   gtok   = (int*)(ws + OFF_GTOK);
  float* ggate  = (float*)(ws + OFF_GGATE);
  u16*   W1T    = (u16*)(ws + OFF_W1T);
  u16*   W2T    = (u16*)(ws + OFF_W2T);
  u16*   W3T    = (u16*)(ws + OFF_W3T);
  u16*   xg     = (u16*)(ws + OFF_XG);
  u16*   h1     = (u16*)(ws + OFF_H1);
  u16*   h2     = (u16*)(ws + OFF_H2);

  hipMemsetAsync(d_out, 0, (size_t)N_TOK * DOUT * sizeof(float), stream);
  hipMemsetAsync(ws + OFF_CTRL, 0, 128, stream);

  conv_w<DIN, H1N><<<dim3(H1N / 64, DIN / 64, NE), 256, 0, stream>>>(W1, W1T);
  conv_w<H1N, H2N><<<dim3(H2N / 64, H1N / 64, NE), 256, 0, stream>>>(W2, W2T);
  conv_w<H2N, DOUT><<<dim3(DOUT / 64, H2N / 64, NE), 256, 0, stream>>>(W3, W3T);

  router_prep<<<64, 256, 0, stream>>>(Wr, br, emb, P, c);
  router_score<<<1024, 256, 0, stream>>>(x, P, c, e01, g01, counts);
  build_offsets<<<1, 64, 0, stream>>>(counts, poff);
  build_lists<<<64, 256, 0, stream>>>(e01, g01, poff, fill, gtok, ggate);
  gather_x<<<CAP / 4, 256, 0, stream>>>(x, poff, counts, gtok, xg);

  gemm_moe<0><<<dim3(H1N / 128, MT), 256, 0, stream>>>(xg, W1T, b1, h1, nullptr,
                                                       poff, counts, nullptr, nullptr, DIN, H1N);
  gemm_moe<0><<<dim3(H2N / 128, MT), 256, 0, stream>>>(h1, W2T, b2, h2, nullptr,
                                                       poff, counts, nullptr, nullptr, H1N, H2N);
  gemm_moe<1><<<dim3(DOUT / 128, MT), 256, 0, stream>>>(h2, W3T, b3, nullptr, out,
                                                        poff, counts, gtok, ggate, H2N, DOUT);
}

// Round 3
// 422.594 us; speedup vs baseline: 2.0852x; 2.0468x over previous
//
#include <hip/hip_runtime.h>

typedef unsigned short u16;
typedef __attribute__((ext_vector_type(8))) short short8;
typedef __attribute__((ext_vector_type(4))) float f32x4;

#define N_TOK 16384
#define DIN   1024
#define NE    16
#define DEMB  128
#define H1N   1024
#define H2N   512
#define DOUT  512
#define CAP   34816   // 32768 entries + 16*128 padding
#define MT    (CAP/128)
#define RBLK  1024    // router blocks (16 tokens each)

// ---- workspace layout (bytes) ----
#define OFF_P      0ul          // 1024*16*4 = 65536
#define OFF_C      65536ul      // 16*4 (pad 256)
#define OFF_CTRL   65792ul      // counts[16]@0, poff[17]@128 (pad 256)
#define OFF_E01    66048ul      // 16384*2*4 = 131072
#define OFF_G01    197120ul     // 131072
#define OFF_GTOK   328192ul     // CAP*4 = 139264
#define OFF_GGATE  467456ul     // 139264
#define OFF_W1T    606720ul     // 16*1024*1024*2 = 33554432
#define OFF_W2T    34161152ul   // 16*512*1024*2 = 16777216
#define OFF_W3T    50938368ul   // 16*512*512*2  = 8388608
#define OFF_XG     59326976ul   // CAP*1024*2 = 71303168
#define OFF_H1     130630144ul  // CAP*1024*2 = 71303168  (ends ~202 MB)
#define OFF_H2     OFF_XG       // h2 aliases xg (disjoint lifetimes)
// bhist/bbase alias head of xg: dead before gather_x writes xg
#define OFF_BH     OFF_XG              // 1024*16*4 = 65536
#define OFF_BB     (OFF_XG + 65536ul)  // 65536

__device__ __forceinline__ u16 f2bf(float f) {
  union { float f; unsigned u; } v; v.f = f;
  unsigned r = v.u + 0x7fff + ((v.u >> 16) & 1);   // RNE, finite inputs
  return (u16)(r >> 16);
}

__device__ __forceinline__ void async_copy16(const u16* g, u16* l) {
  __builtin_amdgcn_global_load_lds((const __attribute__((address_space(1))) unsigned*)g,
                                   (__attribute__((address_space(3))) unsigned*)l,
                                   16, 0, 0);
}

// ---- K0: P = 2*Wr@emb^T [1024][16], c_e = 2*br.emb_e - |emb_e|^2 ----
__global__ void router_prep(const float* __restrict__ Wr, const float* __restrict__ br,
                            const float* __restrict__ emb, float* __restrict__ P,
                            float* __restrict__ c) {
  int idx = blockIdx.x * 256 + threadIdx.x;   // 16384 = 1024 rows * 16 experts
  int row = idx >> 4, e = idx & 15;
  float s = 0.f;
  for (int j = 0; j < DEMB; ++j) s += Wr[row * DEMB + j] * emb[e * DEMB + j];
  P[row * NE + e] = 2.f * s;
  if (idx < NE) {
    float cc = 0.f, n2 = 0.f;
    for (int j = 0; j < DEMB; ++j) {
      float ev = emb[idx * DEMB + j];
      cc += br[j] * ev;
      n2 += ev * ev;
    }
    c[idx] = 2.f * cc - n2;
  }
}

// ---- K1: scores, top-2, gates; per-block LDS histogram -> bhist (NO global atomics) ----
__global__ void __launch_bounds__(256) router_score(
    const float* __restrict__ x, const float* __restrict__ P,
    const float* __restrict__ c, int* __restrict__ e01,
    float* __restrict__ g01, int* __restrict__ bhist) {
  __shared__ float xs[16384];   // 4 waves * 4 tokens * 1024 floats = 64 KB
  __shared__ int lh[16];
  int wave = threadIdx.x >> 6, lane = threadIdx.x & 63;
  int e2 = lane & 7, kgl = lane >> 3;
  int tbase = blockIdx.x * 16 + wave * 4;
  float* xw = xs + wave * 4096;

  if (threadIdx.x < 16) lh[threadIdx.x] = 0;

  // stage 4 token rows, coalesced (1KB per wave-instr)
  #pragma unroll
  for (int t = 0; t < 4; ++t) {
    const float* src = x + (size_t)(tbase + t) * DIN;
    #pragma unroll
    for (int q = 0; q < 4; ++q) {
      int g = q * 256 + lane * 4;
      *(float4*)(xw + t * 1024 + g) = *(const float4*)(src + g);
    }
  }
  __syncthreads();

  int te0 = 2 * e2, te1 = te0 + 1;
  float ce0 = c[te0], ce1 = c[te1];
  const float* Pb = P + te0;          // P is [1024][16]

  float acc0[4] = {0.f, 0.f, 0.f, 0.f};
  float acc1[4] = {0.f, 0.f, 0.f, 0.f};
  int cbase = kgl * 128;
  #pragma unroll 4
  for (int i = 0; i < 32; ++i) {
    int w = (kgl * 4 + i * 4) & 127;   // rotation: conflict-free banks
    int idx = cbase + w;
    float2 pv0 = *(const float2*)(Pb + (size_t)(idx + 0) * NE);
    float2 pv1 = *(const float2*)(Pb + (size_t)(idx + 1) * NE);
    float2 pv2 = *(const float2*)(Pb + (size_t)(idx + 2) * NE);
    float2 pv3 = *(const float2*)(Pb + (size_t)(idx + 3) * NE);
    #pragma unroll
    for (int t = 0; t < 4; ++t) {
      float4 xv = *(const float4*)(xw + t * 1024 + idx);
      acc0[t] = fmaf(xv.x, pv0.x, acc0[t]); acc1[t] = fmaf(xv.x, pv0.y, acc1[t]);
      acc0[t] = fmaf(xv.y, pv1.x, acc0[t]); acc1[t] = fmaf(xv.y, pv1.y, acc1[t]);
      acc0[t] = fmaf(xv.z, pv2.x, acc0[t]); acc1[t] = fmaf(xv.z, pv2.y, acc1[t]);
      acc0[t] = fmaf(xv.w, pv3.x, acc0[t]); acc1[t] = fmaf(xv.w, pv3.y, acc1[t]);
    }
  }

  for (int t = 0; t < 4; ++t) {
    float s0 = acc0[t], s1 = acc1[t];
    // reduce over 8 K-chunks (lane bits 3..5)
    #pragma unroll
    for (int off = 8; off <= 32; off <<= 1) {
      s0 += __shfl_xor(s0, off);
      s1 += __shfl_xor(s1, off);
    }
    s0 += ce0; s1 += ce1;
    float hi; int hidx;
    if (s0 >= s1) { hi = s0; hidx = te0; } else { hi = s1; hidx = te1; }
    float m1 = hi; int i1 = hidx;
    #pragma unroll
    for (int off = 1; off < 8; off <<= 1) {
      float so = __shfl_xor(m1, off); int io = __shfl_xor(i1, off);
      if (so > m1 || (so == m1 && io < i1)) { m1 = so; i1 = io; }
    }
    float c2; int c2i;
    if (i1 == te0)      { c2 = s1; c2i = te1; }
    else if (i1 == te1) { c2 = s0; c2i = te0; }
    else                { c2 = hi; c2i = hidx; }
    float m2 = c2; int i2 = c2i;
    #pragma unroll
    for (int off = 1; off < 8; off <<= 1) {
      float so = __shfl_xor(m2, off); int io = __shfl_xor(i2, off);
      if (so > m2 || (so == m2 && io < i2)) { m2 = so; i2 = io; }
    }
    if (lane == 0) {
      int tok = tbase + t;
      float ev = expf(m2 - m1);
      float inv = 1.f / (1.f + ev);
      e01[tok * 2 + 0] = i1; e01[tok * 2 + 1] = i2;
      g01[tok * 2 + 0] = inv; g01[tok * 2 + 1] = ev * inv;
      atomicAdd(&lh[i1], 1);     // LDS atomic, no global contention
      atomicAdd(&lh[i2], 1);
    }
  }
  __syncthreads();
  if (threadIdx.x < 16) bhist[blockIdx.x * 16 + threadIdx.x] = lh[threadIdx.x];
}

// ---- K2: scan bhist -> counts, poff, per-block bases (1 block, 1024 threads) ----
__global__ void __launch_bounds__(1024) scan_offsets(
    const int* __restrict__ bhist, int* __restrict__ counts,
    int* __restrict__ poff, int* __restrict__ bbase) {
  int t = threadIdx.x;
  int e = t & 15, ch = t >> 4;        // 64 chunks of 16 blocks
  int b0 = ch * 16;
  int s = 0;
  #pragma unroll
  for (int i = 0; i < 16; ++i) s += bhist[(b0 + i) * 16 + e];
  __shared__ int part[64][16];
  __shared__ int chbase[64][16];
  __shared__ int cnt[16];
  __shared__ int pof[16];
  part[ch][e] = s;
  __syncthreads();
  if (t < 16) {
    int run = 0;
    for (int c2 = 0; c2 < 64; ++c2) { chbase[c2][t] = run; run += part[c2][t]; }
    cnt[t] = run;
  }
  __syncthreads();
  if (t == 0) {
    int off = 0;
    for (int e2 = 0; e2 < NE; ++e2) {
      pof[e2] = off;
      poff[e2] = off;
      counts[e2] = cnt[e2];
      off += (cnt[e2] + 127) & ~127;
    }
    poff[NE] = off;
  }
  __syncthreads();
  int run = pof[e] + chbase[ch][e];
  #pragma unroll
  for (int i = 0; i < 16; ++i) {
    bbase[(b0 + i) * 16 + e] = run;
    run += bhist[(b0 + i) * 16 + e];
  }
}

// ---- K3: CSR entry lists (per-block LDS counters seeded from bbase) ----
__global__ void build_lists(const int* __restrict__ e01, const float* __restrict__ g01,
                            const int* __restrict__ bbase, int* __restrict__ gtok,
                            float* __restrict__ ggate) {
  __shared__ int pos[16];
  int tid = threadIdx.x;
  if (tid < 16) pos[tid] = bbase[blockIdx.x * 16 + tid];
  __syncthreads();
  if (tid < 16) {
    int t = blockIdx.x * 16 + tid;
    #pragma unroll
    for (int k = 0; k < 2; ++k) {
      int e = e01[t * 2 + k];
      int p = atomicAdd(&pos[e], 1);
      gtok[p] = t;
      ggate[p] = g01[t * 2 + k];
    }
  }
}

// ---- K4: gather x rows -> bf16 (zeros in padding) ----
__global__ void gather_x(const float* __restrict__ x, const int* __restrict__ poff,
                         const int* __restrict__ counts, const int* __restrict__ gtok,
                         u16* __restrict__ xg) {
  int row = blockIdx.x * 4 + (threadIdx.x >> 6);
  int lane = threadIdx.x & 63;
  int total = poff[NE];
  bool valid = false; int t = 0;
  if (row < total) {
    int e = 0;
    while (row >= poff[e + 1]) ++e;
    if (row - poff[e] < counts[e]) { valid = true; t = gtok[row]; }
  }
  u16* dst = xg + (size_t)row * DIN + lane * 16;
  if (valid) {
    const float* src = x + (size_t)t * DIN + lane * 16;
    #pragma unroll
    for (int j = 0; j < 4; ++j) {
      float4 v = ((const float4*)src)[j];
      ushort4 o;
      o.x = f2bf(v.x); o.y = f2bf(v.y); o.z = f2bf(v.z); o.w = f2bf(v.w);
      ((ushort4*)dst)[j] = o;
    }
  } else {
    ushort4 z = {0, 0, 0, 0};
    #pragma unroll
    for (int j = 0; j < 4; ++j) ((ushort4*)dst)[j] = z;
  }
}

// ---- K5: weight convert+transpose: [E][K][N] f32 -> [E][N][K] bf16 ----
template<int K, int N>
__global__ void conv_w(const float* __restrict__ W, u16* __restrict__ WT) {
  __shared__ float tile[64][65];
  int e = blockIdx.z;
  int n0 = blockIdx.x * 64, k0 = blockIdx.y * 64;
  int tx = threadIdx.x & 63, ty = threadIdx.x >> 6;
  const float* Wb = W + (size_t)e * K * N;
  #pragma unroll
  for (int p = 0; p < 16; ++p) {
    int k = p * 4 + ty;
    tile[k][tx] = Wb[(size_t)(k0 + k) * N + n0 + tx];
  }
  __syncthreads();
  u16* WTb = WT + (size_t)e * N * K;
  #pragma unroll
  for (int p = 0; p < 16; ++p) {
    int n = p * 4 + ty;
    WTb[(size_t)(n0 + n) * K + k0 + tx] = f2bf(tile[tx][n]);
  }
}

// ---- GEMM: A[rows][K] bf16 x B_e[N][K] bf16 (K-contig both) ----
// MODE 0: Cb = bf16(relu(acc+bias)); MODE 1: atomicAdd(out[token], gate*(acc+bias))
template<int MODE>
__global__ void __launch_bounds__(256)
gemm_moe(const u16* __restrict__ A, const u16* __restrict__ Ball,
         const float* __restrict__ bias, u16* __restrict__ Cb, float* __restrict__ outF,
         const int* __restrict__ poff, const int* __restrict__ counts,
         const int* __restrict__ gtok, const float* __restrict__ ggate,
         int K, int N) {
  __shared__ u16 Asm[4096];
  __shared__ u16 Bsm[4096];
  int row_base = blockIdx.y * 128;
  if (row_base >= poff[NE]) return;
  int e = 0;
  while (row_base >= poff[e + 1]) ++e;

  int tid = threadIdx.x;
  int wave = tid >> 6, lane = tid & 63;
  int wm = wave >> 1, wn = wave & 1;
  int fr = lane & 15, kq = lane >> 4;
  int n_base = blockIdx.x * 128;

  const u16* Arow = A + (size_t)row_base * K;
  const u16* Brow = Ball + (size_t)e * N * K + (size_t)n_base * K;

  f32x4 acc[4][4];
  #pragma unroll
  for (int m = 0; m < 4; ++m)
    #pragma unroll
    for (int n = 0; n < 4; ++n)
      acc[m][n] = (f32x4){0.f, 0.f, 0.f, 0.f};

  for (int kt = 0; kt < K; kt += 32) {
    __syncthreads();
    #pragma unroll
    for (int j = 0; j < 2; ++j) {
      int lin = j * 256 + tid;
      int r = lin >> 2, q = lin & 3;
      async_copy16(Arow + (size_t)r * K + kt + q * 8, Asm + lin * 8);
      async_copy16(Brow + (size_t)r * K + kt + q * 8, Bsm + lin * 8);
    }
    __syncthreads();
    short8 av[4], bv[4];
    #pragma unroll
    for (int m = 0; m < 4; ++m)
      av[m] = *(const short8*)(Asm + ((wm * 64 + m * 16 + fr) * 32 + kq * 8));
    #pragma unroll
    for (int n = 0; n < 4; ++n)
      bv[n] = *(const short8*)(Bsm + ((wn * 64 + n * 16 + fr) * 32 + kq * 8));
    #pragma unroll
    for (int m = 0; m < 4; ++m)
      #pragma unroll
      for (int n = 0; n < 4; ++n)
        acc[m][n] = __builtin_amdgcn_mfma_f32_16x16x32_bf16(av[m], bv[n], acc[m][n], 0, 0, 0);
  }

  int crow = (lane >> 4) * 4;   // C/D: col=lane&15, row=(lane>>4)*4+reg
  int ccol = lane & 15;
  const float* be = bias + (size_t)e * N;
  if constexpr (MODE == 0) {
    #pragma unroll
    for (int m = 0; m < 4; ++m) {
      int gr0 = row_base + wm * 64 + m * 16 + crow;
      #pragma unroll
      for (int n = 0; n < 4; ++n) {
        int gc = n_base + wn * 64 + n * 16 + ccol;
        float bvs = be[gc];
        #pragma unroll
        for (int r = 0; r < 4; ++r) {
          float v = acc[m][n][r] + bvs;
          v = v > 0.f ? v : 0.f;
          Cb[(size_t)(gr0 + r) * N + gc] = f2bf(v);
        }
      }
    }
  } else {
    int poe = poff[e], ce = counts[e];
    #pragma unroll
    for (int m = 0; m < 4; ++m) {
      int gr0 = row_base + wm * 64 + m * 16 + crow;
      int tk[4]; float gt[4]; bool vl[4];
      #pragma unroll
      for (int r = 0; r < 4; ++r) {
        int gr = gr0 + r;
        vl[r] = (gr - poe) < ce;
        tk[r] = vl[r] ? gtok[gr] : 0;
        gt[r] = vl[r] ? ggate[gr] : 0.f;
      }
      #pragma unroll
      for (int n = 0; n < 4; ++n) {
        int gc = n_base + wn * 64 + n * 16 + ccol;
        float bvs = be[gc];
        #pragma unroll
        for (int r = 0; r < 4; ++r) {
          if (vl[r]) {
            float v = (acc[m][n][r] + bvs) * gt[r];
            atomicAdd(outF + (size_t)tk[r] * N + gc, v);
          }
        }
      }
    }
  }
}

extern "C" void kernel_launch(void* const* d_in, const int* in_sizes, int n_in,
                              void* d_out, int out_size, void* d_ws, size_t ws_size,
                              hipStream_t stream) {
  const float* x   = (const float*)d_in[0];
  const float* Wr  = (const float*)d_in[1];
  const float* br  = (const float*)d_in[2];
  const float* emb = (const float*)d_in[3];
  const float* W1  = (const float*)d_in[4];
  const float* b1  = (const float*)d_in[5];
  const float* W2  = (const float*)d_in[6];
  const float* b2  = (const float*)d_in[7];
  const float* W3  = (const float*)d_in[8];
  const float* b3  = (const float*)d_in[9];
  float* out = (float*)d_out;
  char* ws = (char*)d_ws;

  float* P      = (float*)(ws + OFF_P);
  float* c      = (float*)(ws + OFF_C);
  int*   counts = (int*)(ws + OFF_CTRL);
  int*   poff   = (int*)(ws + OFF_CTRL + 128);
  int*   e01    = (int*)(ws + OFF_E01);
  float* g01    = (float*)(ws + OFF_G01);
  int*   gtok   = (int*)(ws + OFF_GTOK);
  float* ggate  = (float*)(ws + OFF_GGATE);
  int*   bhist  = (int*)(ws + OFF_BH);
  int*   bbase  = (int*)(ws + OFF_BB);
  u16*   W1T    = (u16*)(ws + OFF_W1T);
  u16*   W2T    = (u16*)(ws + OFF_W2T);
  u16*   W3T    = (u16*)(ws + OFF_W3T);
  u16*   xg     = (u16*)(ws + OFF_XG);
  u16*   h1     = (u16*)(ws + OFF_H1);
  u16*   h2     = (u16*)(ws + OFF_H2);

  hipMemsetAsync(d_out, 0, (size_t)N_TOK * DOUT * sizeof(float), stream);

  conv_w<DIN, H1N><<<dim3(H1N / 64, DIN / 64, NE), 256, 0, stream>>>(W1, W1T);
  conv_w<H1N, H2N><<<dim3(H2N / 64, H1N / 64, NE), 256, 0, stream>>>(W2, W2T);
  conv_w<H2N, DOUT><<<dim3(DOUT / 64, H2N / 64, NE), 256, 0, stream>>>(W3, W3T);

  router_prep<<<64, 256, 0, stream>>>(Wr, br, emb, P, c);
  router_score<<<RBLK, 256, 0, stream>>>(x, P, c, e01, g01, bhist);
  scan_offsets<<<1, 1024, 0, stream>>>(bhist, counts, poff, bbase);
  build_lists<<<RBLK, 64, 0, stream>>>(e01, g01, bbase, gtok, ggate);
  gather_x<<<CAP / 4, 256, 0, stream>>>(x, poff, counts, gtok, xg);

  gemm_moe<0><<<dim3(H1N / 128, MT), 256, 0, stream>>>(xg, W1T, b1, h1, nullptr,
                                                       poff, counts, nullptr, nullptr, DIN, H1N);
  gemm_moe<0><<<dim3(H2N / 128, MT), 256, 0, stream>>>(h1, W2T, b2, h2, nullptr,
                                                       poff, counts, nullptr, nullptr, H1N, H2N);
  gemm_moe<1><<<dim3(DOUT / 128, MT), 256, 0, stream>>>(h2, W3T, b3, nullptr, out,
                                                        poff, counts, gtok, ggate, H2N, DOUT);
}

// Round 4
// 392.591 us; speedup vs baseline: 2.2446x; 1.0764x over previous
//
#include <hip/hip_runtime.h>

typedef unsigned short u16;
typedef __attribute__((ext_vector_type(8))) short short8;
typedef __attribute__((ext_vector_type(4))) float f32x4;

#define N_TOK 16384
#define DIN   1024
#define NE    16
#define DEMB  128
#define H1N   1024
#define H2N   512
#define DOUT  512
#define CAP   34816   // 32768 entries + 16*128 padding
#define MT    (CAP/128)
#define RBLK  1024    // router blocks (16 tokens each)

// ---- workspace layout (bytes) ----
#define OFF_P      0ul          // 1024*16*4 = 65536
#define OFF_C      65536ul      // 16*4 (pad 256)
#define OFF_CTRL   65792ul      // counts[16]@0, poff[17]@128 (pad 256)
#define OFF_E01    66048ul      // 16384*2*4 = 131072
#define OFF_G01    197120ul     // 131072
#define OFF_GTOK   328192ul     // CAP*4 = 139264
#define OFF_GGATE  467456ul     // 139264
#define OFF_W1T    606720ul     // 16*1024*1024*2 = 33554432
#define OFF_W2T    34161152ul   // 16*512*1024*2 = 16777216
#define OFF_W3T    50938368ul   // 16*512*512*2  = 8388608
#define OFF_XG     59326976ul   // CAP*1024*2 = 71303168
#define OFF_H1     130630144ul  // CAP*1024*2 = 71303168  (ends ~202 MB)
#define OFF_H2     OFF_XG       // h2 aliases xg (disjoint lifetimes)
// bhist/bbase alias head of xg: dead before gather_x writes xg
#define OFF_BH     OFF_XG              // 1024*16*4 = 65536
#define OFF_BB     (OFF_XG + 65536ul)  // 65536

__device__ __forceinline__ u16 f2bf(float f) {
  union { float f; unsigned u; } v; v.f = f;
  unsigned r = v.u + 0x7fff + ((v.u >> 16) & 1);   // RNE, finite inputs
  return (u16)(r >> 16);
}

__device__ __forceinline__ void async_copy16(const u16* g, u16* l) {
  __builtin_amdgcn_global_load_lds((const __attribute__((address_space(1))) unsigned*)g,
                                   (__attribute__((address_space(3))) unsigned*)l,
                                   16, 0, 0);
}

// ---- K0: P = 2*Wr@emb^T [1024][16], c_e = 2*br.emb_e - |emb_e|^2 ----
__global__ void router_prep(const float* __restrict__ Wr, const float* __restrict__ br,
                            const float* __restrict__ emb, float* __restrict__ P,
                            float* __restrict__ c) {
  int idx = blockIdx.x * 256 + threadIdx.x;   // 16384 = 1024 rows * 16 experts
  int row = idx >> 4, e = idx & 15;
  float s = 0.f;
  for (int j = 0; j < DEMB; ++j) s += Wr[row * DEMB + j] * emb[e * DEMB + j];
  P[row * NE + e] = 2.f * s;
  if (idx < NE) {
    float cc = 0.f, n2 = 0.f;
    for (int j = 0; j < DEMB; ++j) {
      float ev = emb[idx * DEMB + j];
      cc += br[j] * ev;
      n2 += ev * ev;
    }
    c[idx] = 2.f * cc - n2;
  }
}

// ---- K1: scores, top-2, gates; per-block LDS histogram -> bhist (NO global atomics) ----
__global__ void __launch_bounds__(256) router_score(
    const float* __restrict__ x, const float* __restrict__ P,
    const float* __restrict__ c, int* __restrict__ e01,
    float* __restrict__ g01, int* __restrict__ bhist) {
  __shared__ float xs[16384];   // 4 waves * 4 tokens * 1024 floats = 64 KB
  __shared__ int lh[16];
  int wave = threadIdx.x >> 6, lane = threadIdx.x & 63;
  int e2 = lane & 7, kgl = lane >> 3;
  int tbase = blockIdx.x * 16 + wave * 4;
  float* xw = xs + wave * 4096;

  if (threadIdx.x < 16) lh[threadIdx.x] = 0;

  // stage 4 token rows, coalesced (1KB per wave-instr)
  #pragma unroll
  for (int t = 0; t < 4; ++t) {
    const float* src = x + (size_t)(tbase + t) * DIN;
    #pragma unroll
    for (int q = 0; q < 4; ++q) {
      int g = q * 256 + lane * 4;
      *(float4*)(xw + t * 1024 + g) = *(const float4*)(src + g);
    }
  }
  __syncthreads();

  int te0 = 2 * e2, te1 = te0 + 1;
  float ce0 = c[te0], ce1 = c[te1];
  const float* Pb = P + te0;          // P is [1024][16]

  float acc0[4] = {0.f, 0.f, 0.f, 0.f};
  float acc1[4] = {0.f, 0.f, 0.f, 0.f};
  int cbase = kgl * 128;
  #pragma unroll 4
  for (int i = 0; i < 32; ++i) {
    int w = (kgl * 4 + i * 4) & 127;   // rotation: conflict-free banks
    int idx = cbase + w;
    float2 pv0 = *(const float2*)(Pb + (size_t)(idx + 0) * NE);
    float2 pv1 = *(const float2*)(Pb + (size_t)(idx + 1) * NE);
    float2 pv2 = *(const float2*)(Pb + (size_t)(idx + 2) * NE);
    float2 pv3 = *(const float2*)(Pb + (size_t)(idx + 3) * NE);
    #pragma unroll
    for (int t = 0; t < 4; ++t) {
      float4 xv = *(const float4*)(xw + t * 1024 + idx);
      acc0[t] = fmaf(xv.x, pv0.x, acc0[t]); acc1[t] = fmaf(xv.x, pv0.y, acc1[t]);
      acc0[t] = fmaf(xv.y, pv1.x, acc0[t]); acc1[t] = fmaf(xv.y, pv1.y, acc1[t]);
      acc0[t] = fmaf(xv.z, pv2.x, acc0[t]); acc1[t] = fmaf(xv.z, pv2.y, acc1[t]);
      acc0[t] = fmaf(xv.w, pv3.x, acc0[t]); acc1[t] = fmaf(xv.w, pv3.y, acc1[t]);
    }
  }

  for (int t = 0; t < 4; ++t) {
    float s0 = acc0[t], s1 = acc1[t];
    // reduce over 8 K-chunks (lane bits 3..5)
    #pragma unroll
    for (int off = 8; off <= 32; off <<= 1) {
      s0 += __shfl_xor(s0, off);
      s1 += __shfl_xor(s1, off);
    }
    s0 += ce0; s1 += ce1;
    float hi; int hidx;
    if (s0 >= s1) { hi = s0; hidx = te0; } else { hi = s1; hidx = te1; }
    float m1 = hi; int i1 = hidx;
    #pragma unroll
    for (int off = 1; off < 8; off <<= 1) {
      float so = __shfl_xor(m1, off); int io = __shfl_xor(i1, off);
      if (so > m1 || (so == m1 && io < i1)) { m1 = so; i1 = io; }
    }
    float c2; int c2i;
    if (i1 == te0)      { c2 = s1; c2i = te1; }
    else if (i1 == te1) { c2 = s0; c2i = te0; }
    else                { c2 = hi; c2i = hidx; }
    float m2 = c2; int i2 = c2i;
    #pragma unroll
    for (int off = 1; off < 8; off <<= 1) {
      float so = __shfl_xor(m2, off); int io = __shfl_xor(i2, off);
      if (so > m2 || (so == m2 && io < i2)) { m2 = so; i2 = io; }
    }
    if (lane == 0) {
      int tok = tbase + t;
      float ev = expf(m2 - m1);
      float inv = 1.f / (1.f + ev);
      e01[tok * 2 + 0] = i1; e01[tok * 2 + 1] = i2;
      g01[tok * 2 + 0] = inv; g01[tok * 2 + 1] = ev * inv;
      atomicAdd(&lh[i1], 1);     // LDS atomic, no global contention
      atomicAdd(&lh[i2], 1);
    }
  }
  __syncthreads();
  if (threadIdx.x < 16) bhist[blockIdx.x * 16 + threadIdx.x] = lh[threadIdx.x];
}

// ---- K2: scan bhist -> counts, poff, per-block bases (1 block, 1024 threads) ----
__global__ void __launch_bounds__(1024) scan_offsets(
    const int* __restrict__ bhist, int* __restrict__ counts,
    int* __restrict__ poff, int* __restrict__ bbase) {
  int t = threadIdx.x;
  int e = t & 15, ch = t >> 4;        // 64 chunks of 16 blocks
  int b0 = ch * 16;
  int s = 0;
  #pragma unroll
  for (int i = 0; i < 16; ++i) s += bhist[(b0 + i) * 16 + e];
  __shared__ int part[64][16];
  __shared__ int chbase[64][16];
  __shared__ int cnt[16];
  __shared__ int pof[16];
  part[ch][e] = s;
  __syncthreads();
  if (t < 16) {
    int run = 0;
    for (int c2 = 0; c2 < 64; ++c2) { chbase[c2][t] = run; run += part[c2][t]; }
    cnt[t] = run;
  }
  __syncthreads();
  if (t == 0) {
    int off = 0;
    for (int e2 = 0; e2 < NE; ++e2) {
      pof[e2] = off;
      poff[e2] = off;
      counts[e2] = cnt[e2];
      off += (cnt[e2] + 127) & ~127;
    }
    poff[NE] = off;
  }
  __syncthreads();
  int run = pof[e] + chbase[ch][e];
  #pragma unroll
  for (int i = 0; i < 16; ++i) {
    bbase[(b0 + i) * 16 + e] = run;
    run += bhist[(b0 + i) * 16 + e];
  }
}

// ---- K3: CSR entry lists (per-block LDS counters seeded from bbase) ----
__global__ void build_lists(const int* __restrict__ e01, const float* __restrict__ g01,
                            const int* __restrict__ bbase, int* __restrict__ gtok,
                            float* __restrict__ ggate) {
  __shared__ int pos[16];
  int tid = threadIdx.x;
  if (tid < 16) pos[tid] = bbase[blockIdx.x * 16 + tid];
  __syncthreads();
  if (tid < 16) {
    int t = blockIdx.x * 16 + tid;
    #pragma unroll
    for (int k = 0; k < 2; ++k) {
      int e = e01[t * 2 + k];
      int p = atomicAdd(&pos[e], 1);
      gtok[p] = t;
      ggate[p] = g01[t * 2 + k];
    }
  }
}

// ---- K4: gather x rows -> bf16 (zeros in padding) ----
__global__ void gather_x(const float* __restrict__ x, const int* __restrict__ poff,
                         const int* __restrict__ counts, const int* __restrict__ gtok,
                         u16* __restrict__ xg) {
  int row = blockIdx.x * 4 + (threadIdx.x >> 6);
  int lane = threadIdx.x & 63;
  int total = poff[NE];
  bool valid = false; int t = 0;
  if (row < total) {
    int e = 0;
    while (row >= poff[e + 1]) ++e;
    if (row - poff[e] < counts[e]) { valid = true; t = gtok[row]; }
  }
  u16* dst = xg + (size_t)row * DIN + lane * 16;
  if (valid) {
    const float* src = x + (size_t)t * DIN + lane * 16;
    #pragma unroll
    for (int j = 0; j < 4; ++j) {
      float4 v = ((const float4*)src)[j];
      ushort4 o;
      o.x = f2bf(v.x); o.y = f2bf(v.y); o.z = f2bf(v.z); o.w = f2bf(v.w);
      ((ushort4*)dst)[j] = o;
    }
  } else {
    ushort4 z = {0, 0, 0, 0};
    #pragma unroll
    for (int j = 0; j < 4; ++j) ((ushort4*)dst)[j] = z;
  }
}

// ---- K5: weight convert+transpose: [E][K][N] f32 -> [E][N][K] bf16 ----
template<int K, int N>
__global__ void conv_w(const float* __restrict__ W, u16* __restrict__ WT) {
  __shared__ float tile[64][65];
  int e = blockIdx.z;
  int n0 = blockIdx.x * 64, k0 = blockIdx.y * 64;
  int tx = threadIdx.x & 63, ty = threadIdx.x >> 6;
  const float* Wb = W + (size_t)e * K * N;
  #pragma unroll
  for (int p = 0; p < 16; ++p) {
    int k = p * 4 + ty;
    tile[k][tx] = Wb[(size_t)(k0 + k) * N + n0 + tx];
  }
  __syncthreads();
  u16* WTb = WT + (size_t)e * N * K;
  #pragma unroll
  for (int p = 0; p < 16; ++p) {
    int n = p * 4 + ty;
    WTb[(size_t)(n0 + n) * K + k0 + tx] = f2bf(tile[tx][n]);
  }
}

// ---- GEMM: A[rows][K] bf16 x B_e[N][K] bf16 (K-contig both) ----
// T1: bijective XCD-chunked block remap, nb-fastest (same-A-tile blocks share an XCD L2).
// T2': bank-conflict-free LDS: linear LDS dest (global_load_lds), source chunk permuted
//      slot(row,c) = row*4 + (c ^ ((row>>1)&3)); ds_read applies the same XOR.
// MODE 0: Cb = bf16(relu(acc+bias)); MODE 1: atomicAdd(out[token], gate*(acc+bias))
template<int MODE>
__global__ void __launch_bounds__(256)
gemm_moe(const u16* __restrict__ A, const u16* __restrict__ Ball,
         const float* __restrict__ bias, u16* __restrict__ Cb, float* __restrict__ outF,
         const int* __restrict__ poff, const int* __restrict__ counts,
         const int* __restrict__ gtok, const float* __restrict__ ggate,
         int K, int N, int nblk) {
  __shared__ u16 Asm[4096];
  __shared__ u16 Bsm[4096];

  // bijective XCD remap (m204): consecutive wg land on the same XCD chunk
  int bid = blockIdx.x;
  int q = nblk >> 3, r = nblk & 7;
  int xcd = bid & 7, sidx = bid >> 3;
  int wg = (xcd < r ? xcd * (q + 1) : r * (q + 1) + (xcd - r) * q) + sidx;
  int NB = N >> 7;
  int rb = wg / NB, nb = wg - rb * NB;   // nb fastest: same A-tile contiguous on one XCD

  int row_base = rb * 128;
  if (row_base >= poff[NE]) return;
  int e = 0;
  while (row_base >= poff[e + 1]) ++e;

  int tid = threadIdx.x;
  int wave = tid >> 6, lane = tid & 63;
  int wm = wave >> 1, wn = wave & 1;
  int fr = lane & 15, kq = lane >> 4;
  int n_base = nb * 128;

  const u16* Arow = A + (size_t)row_base * K;
  const u16* Brow = Ball + (size_t)e * N * K + (size_t)n_base * K;

  f32x4 acc[4][4];
  #pragma unroll
  for (int m = 0; m < 4; ++m)
    #pragma unroll
    for (int n = 0; n < 4; ++n)
      acc[m][n] = (f32x4){0.f, 0.f, 0.f, 0.f};

  int swz = (fr >> 1) & 3;                 // = (row>>1)&3 for all fragment rows
  for (int kt = 0; kt < K; kt += 32) {
    __syncthreads();
    #pragma unroll
    for (int j = 0; j < 2; ++j) {
      int lin = j * 256 + tid;
      int rr = lin >> 2, cc = lin & 3;
      int ch = cc ^ ((rr >> 1) & 3);       // source chunk permutation (involution pair)
      async_copy16(Arow + (size_t)rr * K + kt + ch * 8, Asm + lin * 8);
      async_copy16(Brow + (size_t)rr * K + kt + ch * 8, Bsm + lin * 8);
    }
    __syncthreads();
    short8 av[4], bv[4];
    #pragma unroll
    for (int m = 0; m < 4; ++m)
      av[m] = *(const short8*)(Asm + (((wm * 64 + m * 16 + fr) * 4 + (kq ^ swz)) * 8));
    #pragma unroll
    for (int n = 0; n < 4; ++n)
      bv[n] = *(const short8*)(Bsm + (((wn * 64 + n * 16 + fr) * 4 + (kq ^ swz)) * 8));
    #pragma unroll
    for (int m = 0; m < 4; ++m)
      #pragma unroll
      for (int n = 0; n < 4; ++n)
        acc[m][n] = __builtin_amdgcn_mfma_f32_16x16x32_bf16(av[m], bv[n], acc[m][n], 0, 0, 0);
  }

  int crow = (lane >> 4) * 4;   // C/D: col=lane&15, row=(lane>>4)*4+reg
  int ccol = lane & 15;
  const float* be = bias + (size_t)e * N;
  if constexpr (MODE == 0) {
    #pragma unroll
    for (int m = 0; m < 4; ++m) {
      int gr0 = row_base + wm * 64 + m * 16 + crow;
      #pragma unroll
      for (int n = 0; n < 4; ++n) {
        int gc = n_base + wn * 64 + n * 16 + ccol;
        float bvs = be[gc];
        #pragma unroll
        for (int r2 = 0; r2 < 4; ++r2) {
          float v = acc[m][n][r2] + bvs;
          v = v > 0.f ? v : 0.f;
          Cb[(size_t)(gr0 + r2) * N + gc] = f2bf(v);
        }
      }
    }
  } else {
    int poe = poff[e], ce = counts[e];
    #pragma unroll
    for (int m = 0; m < 4; ++m) {
      int gr0 = row_base + wm * 64 + m * 16 + crow;
      int tk[4]; float gt[4]; bool vl[4];
      #pragma unroll
      for (int r2 = 0; r2 < 4; ++r2) {
        int gr = gr0 + r2;
        vl[r2] = (gr - poe) < ce;
        tk[r2] = vl[r2] ? gtok[gr] : 0;
        gt[r2] = vl[r2] ? ggate[gr] : 0.f;
      }
      #pragma unroll
      for (int n = 0; n < 4; ++n) {
        int gc = n_base + wn * 64 + n * 16 + ccol;
        float bvs = be[gc];
        #pragma unroll
        for (int r2 = 0; r2 < 4; ++r2) {
          if (vl[r2]) {
            float v = (acc[m][n][r2] + bvs) * gt[r2];
            atomicAdd(outF + (size_t)tk[r2] * N + gc, v);
          }
        }
      }
    }
  }
}

extern "C" void kernel_launch(void* const* d_in, const int* in_sizes, int n_in,
                              void* d_out, int out_size, void* d_ws, size_t ws_size,
                              hipStream_t stream) {
  const float* x   = (const float*)d_in[0];
  const float* Wr  = (const float*)d_in[1];
  const float* br  = (const float*)d_in[2];
  const float* emb = (const float*)d_in[3];
  const float* W1  = (const float*)d_in[4];
  const float* b1  = (const float*)d_in[5];
  const float* W2  = (const float*)d_in[6];
  const float* b2  = (const float*)d_in[7];
  const float* W3  = (const float*)d_in[8];
  const float* b3  = (const float*)d_in[9];
  float* out = (float*)d_out;
  char* ws = (char*)d_ws;

  float* P      = (float*)(ws + OFF_P);
  float* c      = (float*)(ws + OFF_C);
  int*   counts = (int*)(ws + OFF_CTRL);
  int*   poff   = (int*)(ws + OFF_CTRL + 128);
  int*   e01    = (int*)(ws + OFF_E01);
  float* g01    = (float*)(ws + OFF_G01);
  int*   gtok   = (int*)(ws + OFF_GTOK);
  float* ggate  = (float*)(ws + OFF_GGATE);
  int*   bhist  = (int*)(ws + OFF_BH);
  int*   bbase  = (int*)(ws + OFF_BB);
  u16*   W1T    = (u16*)(ws + OFF_W1T);
  u16*   W2T    = (u16*)(ws + OFF_W2T);
  u16*   W3T    = (u16*)(ws + OFF_W3T);
  u16*   xg     = (u16*)(ws + OFF_XG);
  u16*   h1     = (u16*)(ws + OFF_H1);
  u16*   h2     = (u16*)(ws + OFF_H2);

  hipMemsetAsync(d_out, 0, (size_t)N_TOK * DOUT * sizeof(float), stream);

  conv_w<DIN, H1N><<<dim3(H1N / 64, DIN / 64, NE), 256, 0, stream>>>(W1, W1T);
  conv_w<H1N, H2N><<<dim3(H2N / 64, H1N / 64, NE), 256, 0, stream>>>(W2, W2T);
  conv_w<H2N, DOUT><<<dim3(DOUT / 64, H2N / 64, NE), 256, 0, stream>>>(W3, W3T);

  router_prep<<<64, 256, 0, stream>>>(Wr, br, emb, P, c);
  router_score<<<RBLK, 256, 0, stream>>>(x, P, c, e01, g01, bhist);
  scan_offsets<<<1, 1024, 0, stream>>>(bhist, counts, poff, bbase);
  build_lists<<<RBLK, 64, 0, stream>>>(e01, g01, bbase, gtok, ggate);
  gather_x<<<CAP / 4, 256, 0, stream>>>(x, poff, counts, gtok, xg);

  int nb1 = (H1N / 128) * MT;
  int nb2 = (H2N / 128) * MT;
  int nb3 = (DOUT / 128) * MT;
  gemm_moe<0><<<nb1, 256, 0, stream>>>(xg, W1T, b1, h1, nullptr,
                                       poff, counts, nullptr, nullptr, DIN, H1N, nb1);
  gemm_moe<0><<<nb2, 256, 0, stream>>>(h1, W2T, b2, h2, nullptr,
                                       poff, counts, nullptr, nullptr, H1N, H2N, nb2);
  gemm_moe<1><<<nb3, 256, 0, stream>>>(h2, W3T, b3, nullptr, out,
                                       poff, counts, gtok, ggate, H2N, DOUT, nb3);
}